// Round 3
// baseline (189.500 us; speedup 1.0000x reference)
//
#include <hip/hip_runtime.h>

#define IMG_H 480
#define IMG_W 480
#define ATT_H 30
#define ATT_W 30
#define ATT_N (ATT_H * ATT_W)
#define PAD 48
#define NCH 3
#define NB 32
#define STRIPS 32           // 480 rows / 15 rows per strip
#define ROWS_PER_STRIP 15

// Kernel 1: per-strip mask bbox. Each block computes theta (0.5*max) itself
// (deterministic, identical across blocks) and writes its strip's raw bbox to
// a private slot — no global atomics, no init dependency on ws contents.
__global__ void __launch_bounds__(256) mask_kernel(const float* __restrict__ atten,
                                                   int* __restrict__ strip_box) {
    const int strip = blockIdx.x;
    const int b = blockIdx.y;
    const int tid = threadIdx.x;
    __shared__ float s_att[ATT_N];
    __shared__ float s_red[4];
    __shared__ int s_box[4];   // minr, maxr, minc, maxc

    const float* a = atten + (size_t)b * ATT_N;
    for (int i = tid; i < ATT_N; i += 256) s_att[i] = a[i];
    if (tid == 0) { s_box[0] = IMG_H; s_box[1] = -1; s_box[2] = IMG_W; s_box[3] = -1; }
    __syncthreads();

    // block max over the 900 attention values (order-independent => exact)
    float m = -1e30f;
    for (int i = tid; i < ATT_N; i += 256) m = fmaxf(m, s_att[i]);
    #pragma unroll
    for (int off = 32; off > 0; off >>= 1) m = fmaxf(m, __shfl_down(m, off, 64));
    if ((tid & 63) == 0) s_red[tid >> 6] = m;
    __syncthreads();
    const float theta = 0.5f * fmaxf(fmaxf(s_red[0], s_red[1]), fmaxf(s_red[2], s_red[3]));

    const int y_base = strip * ROWS_PER_STRIP;
    int minr = IMG_H, maxr = -1, minc = IMG_W, maxc = -1;
    for (int p = tid; p < ROWS_PER_STRIP * IMG_W; p += 256) {
        const int yy = p / IMG_W;
        const int y = y_base + yy;
        const int x = p - yy * IMG_W;
        // source coords: (i+0.5)*(30/480) - 0.5, clipped — scale is exactly 1/16
        float sy = (y + 0.5f) * 0.0625f - 0.5f;
        sy = fminf(fmaxf(sy, 0.0f), (float)(ATT_H - 1));
        const float fy0 = floorf(sy);
        const int r0 = (int)fy0;
        const int r1 = min(r0 + 1, ATT_H - 1);
        const float wr = sy - fy0;

        float sx = (x + 0.5f) * 0.0625f - 0.5f;
        sx = fminf(fmaxf(sx, 0.0f), (float)(ATT_W - 1));
        const float fx0 = floorf(sx);
        const int c0 = (int)fx0;
        const int c1 = min(c0 + 1, ATT_W - 1);
        const float wc = sx - fx0;

        // same op order as reference: row blend first, then column blend
        const float rb0 = s_att[r0 * ATT_W + c0] * (1.0f - wr) + s_att[r1 * ATT_W + c0] * wr;
        const float rb1 = s_att[r0 * ATT_W + c1] * (1.0f - wr) + s_att[r1 * ATT_W + c1] * wr;
        const float v = rb0 * (1.0f - wc) + rb1 * wc;
        if (v >= theta) {
            minr = min(minr, y); maxr = max(maxr, y);
            minc = min(minc, x); maxc = max(maxc, x);
        }
    }
    atomicMin(&s_box[0], minr); atomicMax(&s_box[1], maxr);
    atomicMin(&s_box[2], minc); atomicMax(&s_box[3], maxc);
    __syncthreads();
    if (tid == 0) {
        int* dst = strip_box + ((size_t)b * STRIPS + strip) * 4;
        dst[0] = s_box[0]; dst[1] = s_box[1]; dst[2] = s_box[2]; dst[3] = s_box[3];
    }
}

// Kernel 1.5: per-image prep. Reduce the strip bboxes once per image and
// precompute the bilinear coordinate tables:
//   rowtab[b][y] = {r0, r1, bits(wr), 0}
//   coltab[b][x] = {c0, c1, bits(wc), 0}
// These were previously recomputed by every (b,y) blend block (~10 VALU +
// 2 cvts per pixel-iter, plus a 64-load bbox reduce per block) — pure
// VALU-issue fat, which the counters say is the binding axis (VALUBusy ~50%
// while BW/conflicts/occupancy changes were all neutral).
// Values computed with the EXACT same f32 expressions as before => bit-exact.
__global__ void __launch_bounds__(512) prep_kernel(const int* __restrict__ strip_box,
                                                   int4* __restrict__ rowtab,
                                                   int4* __restrict__ coltab) {
    const int b = blockIdx.x;
    const int tid = threadIdx.x;

    int minr = IMG_H, maxr = -1, minc = IMG_W, maxc = -1;
    const int* sb = strip_box + (size_t)b * STRIPS * 4;
    #pragma unroll
    for (int s = 0; s < STRIPS; ++s) {
        minr = min(minr, sb[s * 4 + 0]); maxr = max(maxr, sb[s * 4 + 1]);
        minc = min(minc, sb[s * 4 + 2]); maxc = max(maxc, sb[s * 4 + 3]);
    }
    const int h0 = max(minr - PAD, 0);
    const int h1 = min(maxr + PAD, IMG_H);
    const int w0 = max(minc - PAD, 0);
    const int w1 = min(maxc + PAD, IMG_W);
    const float cropH = (float)(h1 - h0);
    const float cropW = (float)(w1 - w0);

    if (tid < IMG_H) {
        // row entry (reference op order, identical expressions to old blend)
        float sy = (tid + 0.5f) * (cropH / (float)IMG_H) - 0.5f;
        sy = fminf(fmaxf(sy, 0.0f), cropH - 1.0f);
        const float fy0 = floorf(sy);
        const float fy1 = fminf(fy0 + 1.0f, cropH - 1.0f);
        const float wr = sy - fy0;
        rowtab[(size_t)b * IMG_H + tid] =
            make_int4(h0 + (int)fy0, h0 + (int)fy1, __float_as_int(wr), 0);

        // col entry
        float sx = (tid + 0.5f) * (cropW / (float)IMG_W) - 0.5f;
        sx = fminf(fmaxf(sx, 0.0f), cropW - 1.0f);
        const float fx0 = floorf(sx);
        const float fx1 = fminf(fx0 + 1.0f, cropW - 1.0f);
        const float wc = sx - fx0;
        coltab[(size_t)b * IMG_W + tid] =
            make_int4(w0 + (int)fx0, w0 + (int)fx1, __float_as_int(wc), 0);
    }
}

// Kernel 2: one block per (b, y) output row, all 3 channels. Identical
// structure to round-1 (no swizzle — R2 showed it reduces FETCH but costs
// time). Only change: all coordinate math and the bbox reduce are replaced by
// one uniform s_load (rowtab) + one coalesced L2-resident int4 load per
// pixel-iter (coltab).
__global__ void __launch_bounds__(256) blend_kernel(const float* __restrict__ images,
                                                    const int4* __restrict__ rowtab,
                                                    const int4* __restrict__ coltab,
                                                    float* __restrict__ out) {
    const int y = blockIdx.x;
    const int b = blockIdx.y;
    const int tid = threadIdx.x;
    __shared__ __align__(16) float s_rows[NCH][2][IMG_W];   // 11520 B

    const int4 rt = rowtab[(size_t)b * IMG_H + y];   // uniform address => s_load
    const int r0 = rt.x;
    const int r1 = rt.y;
    const float wr = __int_as_float(rt.z);
    const float omwr = 1.0f - wr;

    const float* imgb = images + (size_t)b * NCH * IMG_H * IMG_W;

    // stage source rows r0,r1 for all 3 channels: 6 rows x 120 float4 = 720
    for (int i = tid; i < 6 * (IMG_W / 4); i += 256) {
        const int rowid = i / (IMG_W / 4);       // 0..5
        const int q = i - rowid * (IMG_W / 4);   // 0..119
        const int ch = rowid >> 1;
        const int r = (rowid & 1) ? r1 : r0;
        ((float4*)&s_rows[ch][rowid & 1][0])[q] =
            ((const float4*)(imgb + ((size_t)ch * IMG_H + r) * IMG_W))[q];
    }
    __syncthreads();

    const int4* ct = coltab + (size_t)b * IMG_W;
    for (int x = tid; x < IMG_W; x += 256) {
        const int4 cc = ct[x];
        const int c0 = cc.x;
        const int c1 = cc.y;
        const float wc = __int_as_float(cc.z);
        const float omwc = 1.0f - wc;

        #pragma unroll
        for (int ch = 0; ch < NCH; ++ch) {
            const float v00 = s_rows[ch][0][c0];
            const float v10 = s_rows[ch][1][c0];
            const float v01 = s_rows[ch][0][c1];
            const float v11 = s_rows[ch][1][c1];
            const float rb0 = v00 * omwr + v10 * wr;
            const float rb1 = v01 * omwr + v11 * wr;
            const float patch = rb0 * omwc + rb1 * wc;
            const size_t off = ((size_t)b * NCH + ch) * (IMG_H * IMG_W)
                             + (size_t)y * IMG_W + x;
            const float base = images[off];
            out[off] = base * 0.6f + patch * 0.4f;
        }
    }
}

extern "C" void kernel_launch(void* const* d_in, const int* in_sizes, int n_in,
                              void* d_out, int out_size, void* d_ws, size_t ws_size,
                              hipStream_t stream) {
    const float* images = (const float*)d_in[0];
    const float* atten  = (const float*)d_in[1];
    float* out = (float*)d_out;
    // workspace layout:
    //   [0, 16384)            strip_box: 32 * 32 * 4 ints
    //   [16384, 262144)       rowtab: 32 * 480 int4
    //   [262144, 507904)      coltab: 32 * 480 int4
    int* strip_box = (int*)d_ws;
    int4* rowtab = (int4*)((char*)d_ws + 16384);
    int4* coltab = (int4*)((char*)d_ws + 16384 + 32 * IMG_H * (int)sizeof(int4));

    dim3 mgrid(STRIPS, NB);
    mask_kernel<<<mgrid, 256, 0, stream>>>(atten, strip_box);

    prep_kernel<<<dim3(NB), 512, 0, stream>>>(strip_box, rowtab, coltab);

    dim3 bgrid(IMG_H, NB);
    blend_kernel<<<bgrid, 256, 0, stream>>>(images, rowtab, coltab, out);
}

// Round 4
// 186.230 us; speedup vs baseline: 1.0176x; 1.0176x over previous
//
#include <hip/hip_runtime.h>

#define IMG_H 480
#define IMG_W 480
#define ATT_H 30
#define ATT_W 30
#define ATT_N (ATT_H * ATT_W)
#define PAD 48
#define NCH 3
#define NB 32
#define STRIPS 32           // 480 rows / 15 rows per strip
#define ROWS_PER_STRIP 15

// Kernel 1: per-strip mask bbox. Each block computes theta (0.5*max) itself
// (deterministic, identical across blocks) and writes its strip's raw bbox to
// a private slot — no global atomics, no init dependency on ws contents.
__global__ void __launch_bounds__(256) mask_kernel(const float* __restrict__ atten,
                                                   int* __restrict__ strip_box) {
    const int strip = blockIdx.x;
    const int b = blockIdx.y;
    const int tid = threadIdx.x;
    __shared__ float s_att[ATT_N];
    __shared__ float s_red[4];
    __shared__ int s_box[4];   // minr, maxr, minc, maxc

    const float* a = atten + (size_t)b * ATT_N;
    for (int i = tid; i < ATT_N; i += 256) s_att[i] = a[i];
    if (tid == 0) { s_box[0] = IMG_H; s_box[1] = -1; s_box[2] = IMG_W; s_box[3] = -1; }
    __syncthreads();

    // block max over the 900 attention values (order-independent => exact)
    float m = -1e30f;
    for (int i = tid; i < ATT_N; i += 256) m = fmaxf(m, s_att[i]);
    #pragma unroll
    for (int off = 32; off > 0; off >>= 1) m = fmaxf(m, __shfl_down(m, off, 64));
    if ((tid & 63) == 0) s_red[tid >> 6] = m;
    __syncthreads();
    const float theta = 0.5f * fmaxf(fmaxf(s_red[0], s_red[1]), fmaxf(s_red[2], s_red[3]));

    const int y_base = strip * ROWS_PER_STRIP;
    int minr = IMG_H, maxr = -1, minc = IMG_W, maxc = -1;
    for (int p = tid; p < ROWS_PER_STRIP * IMG_W; p += 256) {
        const int yy = p / IMG_W;
        const int y = y_base + yy;
        const int x = p - yy * IMG_W;
        // source coords: (i+0.5)*(30/480) - 0.5, clipped — scale is exactly 1/16
        float sy = (y + 0.5f) * 0.0625f - 0.5f;
        sy = fminf(fmaxf(sy, 0.0f), (float)(ATT_H - 1));
        const float fy0 = floorf(sy);
        const int r0 = (int)fy0;
        const int r1 = min(r0 + 1, ATT_H - 1);
        const float wr = sy - fy0;

        float sx = (x + 0.5f) * 0.0625f - 0.5f;
        sx = fminf(fmaxf(sx, 0.0f), (float)(ATT_W - 1));
        const float fx0 = floorf(sx);
        const int c0 = (int)fx0;
        const int c1 = min(c0 + 1, ATT_W - 1);
        const float wc = sx - fx0;

        // same op order as reference: row blend first, then column blend
        const float rb0 = s_att[r0 * ATT_W + c0] * (1.0f - wr) + s_att[r1 * ATT_W + c0] * wr;
        const float rb1 = s_att[r0 * ATT_W + c1] * (1.0f - wr) + s_att[r1 * ATT_W + c1] * wr;
        const float v = rb0 * (1.0f - wc) + rb1 * wc;
        if (v >= theta) {
            minr = min(minr, y); maxr = max(maxr, y);
            minc = min(minc, x); maxc = max(maxc, x);
        }
    }
    atomicMin(&s_box[0], minr); atomicMax(&s_box[1], maxr);
    atomicMin(&s_box[2], minc); atomicMax(&s_box[3], maxc);
    __syncthreads();
    if (tid == 0) {
        int* dst = strip_box + ((size_t)b * STRIPS + strip) * 4;
        dst[0] = s_box[0]; dst[1] = s_box[1]; dst[2] = s_box[2]; dst[3] = s_box[3];
    }
}

// Kernel 1.5: per-image prep. Reduce the strip bboxes once per image and
// precompute the bilinear coordinate tables (bit-exact same expressions):
//   rowtab[b][y] = {r0, r1, bits(wr), 0}
//   coltab[b][x] = {c0, c1, bits(wc), 0}
__global__ void __launch_bounds__(512) prep_kernel(const int* __restrict__ strip_box,
                                                   int4* __restrict__ rowtab,
                                                   int4* __restrict__ coltab) {
    const int b = blockIdx.x;
    const int tid = threadIdx.x;

    int minr = IMG_H, maxr = -1, minc = IMG_W, maxc = -1;
    const int* sb = strip_box + (size_t)b * STRIPS * 4;
    #pragma unroll
    for (int s = 0; s < STRIPS; ++s) {
        minr = min(minr, sb[s * 4 + 0]); maxr = max(maxr, sb[s * 4 + 1]);
        minc = min(minc, sb[s * 4 + 2]); maxc = max(maxc, sb[s * 4 + 3]);
    }
    const int h0 = max(minr - PAD, 0);
    const int h1 = min(maxr + PAD, IMG_H);
    const int w0 = max(minc - PAD, 0);
    const int w1 = min(maxc + PAD, IMG_W);
    const float cropH = (float)(h1 - h0);
    const float cropW = (float)(w1 - w0);

    if (tid < IMG_H) {
        // row entry (reference op order, identical expressions to old blend)
        float sy = (tid + 0.5f) * (cropH / (float)IMG_H) - 0.5f;
        sy = fminf(fmaxf(sy, 0.0f), cropH - 1.0f);
        const float fy0 = floorf(sy);
        const float fy1 = fminf(fy0 + 1.0f, cropH - 1.0f);
        const float wr = sy - fy0;
        rowtab[(size_t)b * IMG_H + tid] =
            make_int4(h0 + (int)fy0, h0 + (int)fy1, __float_as_int(wr), 0);

        // col entry
        float sx = (tid + 0.5f) * (cropW / (float)IMG_W) - 0.5f;
        sx = fminf(fmaxf(sx, 0.0f), cropW - 1.0f);
        const float fx0 = floorf(sx);
        const float fx1 = fminf(fx0 + 1.0f, cropW - 1.0f);
        const float wc = sx - fx0;
        coltab[(size_t)b * IMG_W + tid] =
            make_int4(w0 + (int)fx0, w0 + (int)fx1, __float_as_int(wc), 0);
    }
}

// Kernel 2 — ROUND 4: barrier-free. Three rounds proved the targeted resources
// (LDS conflicts, DRAM bytes, VALU issue) were each freed with ZERO effect on
// duration; every throughput counter sits well under its ceiling. The one
// structure shared by all prior versions is stage->__syncthreads->gather:
// all 4 waves of a block drain vmcnt together at the barrier, and co-resident
// blocks phase-lock, so the CU alternates between "all waiting" and "all
// computing". This version deletes LDS+barrier entirely: each thread gathers
// its 12 taps + 3 base pixels directly from global (L1/L2-cached; tap lane
// stride ~1). ~15 independent loads in flight per thread => latency hidden by
// MLP x TLP with no drain point. Identical memory values, identical arithmetic
// expressions => bit-exact output.
__global__ void __launch_bounds__(256) blend_kernel(const float* __restrict__ images,
                                                    const int4* __restrict__ rowtab,
                                                    const int4* __restrict__ coltab,
                                                    float* __restrict__ out) {
    const int y = blockIdx.x;
    const int b = blockIdx.y;
    const int tid = threadIdx.x;

    const int4 rt = rowtab[(size_t)b * IMG_H + y];   // uniform => scalar load
    const int r0 = rt.x;
    const int r1 = rt.y;
    const float wr = __int_as_float(rt.z);
    const float omwr = 1.0f - wr;

    const float* imgb = images + (size_t)b * NCH * IMG_H * IMG_W;
    float* outb = out + (size_t)b * NCH * IMG_H * IMG_W;
    const int4* ct = coltab + (size_t)b * IMG_W;

    #pragma unroll
    for (int half = 0; half < 2; ++half) {
        const int x = tid + half * 256;
        if (x < IMG_W) {
            const int4 cc = ct[x];
            const int c0 = cc.x;
            const int c1 = cc.y;
            const float wc = __int_as_float(cc.z);
            const float omwc = 1.0f - wc;

            #pragma unroll
            for (int ch = 0; ch < NCH; ++ch) {
                const float* p = imgb + (size_t)ch * (IMG_H * IMG_W);
                const float v00 = p[r0 * IMG_W + c0];
                const float v10 = p[r1 * IMG_W + c0];
                const float v01 = p[r0 * IMG_W + c1];
                const float v11 = p[r1 * IMG_W + c1];
                const float rb0 = v00 * omwr + v10 * wr;
                const float rb1 = v01 * omwr + v11 * wr;
                const float patch = rb0 * omwc + rb1 * wc;
                const size_t off = (size_t)ch * (IMG_H * IMG_W)
                                 + (size_t)y * IMG_W + x;
                outb[off] = imgb[off] * 0.6f + patch * 0.4f;
            }
        }
    }
}

extern "C" void kernel_launch(void* const* d_in, const int* in_sizes, int n_in,
                              void* d_out, int out_size, void* d_ws, size_t ws_size,
                              hipStream_t stream) {
    const float* images = (const float*)d_in[0];
    const float* atten  = (const float*)d_in[1];
    float* out = (float*)d_out;
    // workspace layout:
    //   [0, 16384)            strip_box: 32 * 32 * 4 ints
    //   [16384, 262144)       rowtab: 32 * 480 int4
    //   [262144, 507904)      coltab: 32 * 480 int4
    int* strip_box = (int*)d_ws;
    int4* rowtab = (int4*)((char*)d_ws + 16384);
    int4* coltab = (int4*)((char*)d_ws + 16384 + 32 * IMG_H * (int)sizeof(int4));

    dim3 mgrid(STRIPS, NB);
    mask_kernel<<<mgrid, 256, 0, stream>>>(atten, strip_box);

    prep_kernel<<<dim3(NB), 512, 0, stream>>>(strip_box, rowtab, coltab);

    dim3 bgrid(IMG_H, NB);
    blend_kernel<<<bgrid, 256, 0, stream>>>(images, rowtab, coltab, out);
}

// Round 5
// 184.498 us; speedup vs baseline: 1.0271x; 1.0094x over previous
//
#include <hip/hip_runtime.h>

#define IMG_H 480
#define IMG_W 480
#define ATT_H 30
#define ATT_W 30
#define ATT_N (ATT_H * ATT_W)
#define PAD 48
#define NCH 3
#define NB 32
#define STRIPS 32           // 480 rows / 15 rows per strip
#define ROWS_PER_STRIP 15

#define FP4_PER_ROW (IMG_W / 4)              // 120
#define FP4_PER_CH  (IMG_H * FP4_PER_ROW)    // 57600
#define FP4_PER_IMG (NCH * FP4_PER_CH)       // 172800
#define FP4_TOTAL   (NB * FP4_PER_IMG)       // 5529600

// Kernel 1: per-strip mask bbox. Each block computes theta (0.5*max) itself
// (deterministic, identical across blocks) and writes its strip's raw bbox to
// a private slot — no global atomics, no init dependency on ws contents.
__global__ void __launch_bounds__(256) mask_kernel(const float* __restrict__ atten,
                                                   int* __restrict__ strip_box) {
    const int strip = blockIdx.x;
    const int b = blockIdx.y;
    const int tid = threadIdx.x;
    __shared__ float s_att[ATT_N];
    __shared__ float s_red[4];
    __shared__ int s_box[4];   // minr, maxr, minc, maxc

    const float* a = atten + (size_t)b * ATT_N;
    for (int i = tid; i < ATT_N; i += 256) s_att[i] = a[i];
    if (tid == 0) { s_box[0] = IMG_H; s_box[1] = -1; s_box[2] = IMG_W; s_box[3] = -1; }
    __syncthreads();

    // block max over the 900 attention values (order-independent => exact)
    float m = -1e30f;
    for (int i = tid; i < ATT_N; i += 256) m = fmaxf(m, s_att[i]);
    #pragma unroll
    for (int off = 32; off > 0; off >>= 1) m = fmaxf(m, __shfl_down(m, off, 64));
    if ((tid & 63) == 0) s_red[tid >> 6] = m;
    __syncthreads();
    const float theta = 0.5f * fmaxf(fmaxf(s_red[0], s_red[1]), fmaxf(s_red[2], s_red[3]));

    const int y_base = strip * ROWS_PER_STRIP;
    int minr = IMG_H, maxr = -1, minc = IMG_W, maxc = -1;
    for (int p = tid; p < ROWS_PER_STRIP * IMG_W; p += 256) {
        const int yy = p / IMG_W;
        const int y = y_base + yy;
        const int x = p - yy * IMG_W;
        // source coords: (i+0.5)*(30/480) - 0.5, clipped — scale is exactly 1/16
        float sy = (y + 0.5f) * 0.0625f - 0.5f;
        sy = fminf(fmaxf(sy, 0.0f), (float)(ATT_H - 1));
        const float fy0 = floorf(sy);
        const int r0 = (int)fy0;
        const int r1 = min(r0 + 1, ATT_H - 1);
        const float wr = sy - fy0;

        float sx = (x + 0.5f) * 0.0625f - 0.5f;
        sx = fminf(fmaxf(sx, 0.0f), (float)(ATT_W - 1));
        const float fx0 = floorf(sx);
        const int c0 = (int)fx0;
        const int c1 = min(c0 + 1, ATT_W - 1);
        const float wc = sx - fx0;

        // same op order as reference: row blend first, then column blend
        const float rb0 = s_att[r0 * ATT_W + c0] * (1.0f - wr) + s_att[r1 * ATT_W + c0] * wr;
        const float rb1 = s_att[r0 * ATT_W + c1] * (1.0f - wr) + s_att[r1 * ATT_W + c1] * wr;
        const float v = rb0 * (1.0f - wc) + rb1 * wc;
        if (v >= theta) {
            minr = min(minr, y); maxr = max(maxr, y);
            minc = min(minc, x); maxc = max(maxc, x);
        }
    }
    atomicMin(&s_box[0], minr); atomicMax(&s_box[1], maxr);
    atomicMin(&s_box[2], minc); atomicMax(&s_box[3], maxc);
    __syncthreads();
    if (tid == 0) {
        int* dst = strip_box + ((size_t)b * STRIPS + strip) * 4;
        dst[0] = s_box[0]; dst[1] = s_box[1]; dst[2] = s_box[2]; dst[3] = s_box[3];
    }
}

// Kernel 1.5: per-image prep. Reduce strip bboxes, precompute bilinear tables
// (bit-exact same expressions), and detect the DEGENERATE full-crop case:
// h0==0 && h1==H && w0==0 && w1==W  =>  scale==1 exactly => sy==y, sx==x,
// wr==wc==0 => the reference's patch equals base BITWISE (all other taps have
// exact 0.0 weights; only -0.0 -> +0.0 can differ, absdiff 0). Flag goes in
// rowtab[.].w (previously unused) so blend needs no extra load.
__global__ void __launch_bounds__(512) prep_kernel(const int* __restrict__ strip_box,
                                                   int4* __restrict__ rowtab,
                                                   int4* __restrict__ coltab) {
    const int b = blockIdx.x;
    const int tid = threadIdx.x;

    int minr = IMG_H, maxr = -1, minc = IMG_W, maxc = -1;
    const int* sb = strip_box + (size_t)b * STRIPS * 4;
    #pragma unroll
    for (int s = 0; s < STRIPS; ++s) {
        minr = min(minr, sb[s * 4 + 0]); maxr = max(maxr, sb[s * 4 + 1]);
        minc = min(minc, sb[s * 4 + 2]); maxc = max(maxc, sb[s * 4 + 3]);
    }
    const int h0 = max(minr - PAD, 0);
    const int h1 = min(maxr + PAD, IMG_H);
    const int w0 = max(minc - PAD, 0);
    const int w1 = min(maxc + PAD, IMG_W);
    const float cropH = (float)(h1 - h0);
    const float cropW = (float)(w1 - w0);
    const int full = (h0 == 0 && h1 == IMG_H && w0 == 0 && w1 == IMG_W) ? 1 : 0;

    if (tid < IMG_H) {
        // row entry (reference op order, identical expressions to old blend)
        float sy = (tid + 0.5f) * (cropH / (float)IMG_H) - 0.5f;
        sy = fminf(fmaxf(sy, 0.0f), cropH - 1.0f);
        const float fy0 = floorf(sy);
        const float fy1 = fminf(fy0 + 1.0f, cropH - 1.0f);
        const float wr = sy - fy0;
        rowtab[(size_t)b * IMG_H + tid] =
            make_int4(h0 + (int)fy0, h0 + (int)fy1, __float_as_int(wr), full);

        // col entry
        float sx = (tid + 0.5f) * (cropW / (float)IMG_W) - 0.5f;
        sx = fminf(fmaxf(sx, 0.0f), cropW - 1.0f);
        const float fx0 = floorf(sx);
        const float fx1 = fminf(fx0 + 1.0f, cropW - 1.0f);
        const float wc = sx - fx0;
        coltab[(size_t)b * IMG_W + tid] =
            make_int4(w0 + (int)fx0, w0 + (int)fx1, __float_as_int(wc), 0);
    }
}

// Kernel 2 — ROUND 5: grid-stride float4 with per-image degenerate fast path.
// Five structurally different general paths all pinned at 54-57us with every
// pipe <=50% of ceiling. On this workload every crop is the FULL image (random
// attention => bbox spans the map => +-48 pad => [0,480)x[0,480)), where the
// reference arithmetic collapses bitwise to out = base*0.6 + base*0.4. Fast
// path = pure float4 stream (m13-copy shape, ~6.3 TB/s achievable). Non-full
// images take the exact round-4 general path (same tables, same expressions)
// => correctness is data-independent.
__global__ void __launch_bounds__(256) blend_kernel(const float* __restrict__ images,
                                                    const int4* __restrict__ rowtab,
                                                    const int4* __restrict__ coltab,
                                                    float* __restrict__ out) {
    for (int chunk = blockIdx.x * blockDim.x + threadIdx.x; chunk < FP4_TOTAL;
         chunk += gridDim.x * blockDim.x) {
        const int b    = chunk / FP4_PER_IMG;
        const int rem  = chunk - b * FP4_PER_IMG;
        const int ch   = rem / FP4_PER_CH;
        const int rem2 = rem - ch * FP4_PER_CH;
        const int y    = rem2 / FP4_PER_ROW;
        const int xq   = rem2 - y * FP4_PER_ROW;

        const int4 rt = rowtab[b * IMG_H + y];            // L1/L2-hit, 16B
        const float4 base = ((const float4*)images)[chunk];
        float4 res;

        if (rt.w) {
            // full-crop: patch == base bitwise (see prep_kernel comment)
            res.x = base.x * 0.6f + base.x * 0.4f;
            res.y = base.y * 0.6f + base.y * 0.4f;
            res.z = base.z * 0.6f + base.z * 0.4f;
            res.w = base.w * 0.6f + base.w * 0.4f;
        } else {
            const int r0 = rt.x;
            const int r1 = rt.y;
            const float wr = __int_as_float(rt.z);
            const float omwr = 1.0f - wr;
            const float* p = images + ((size_t)b * NCH + ch) * (IMG_H * IMG_W);
            const int4* ctb = coltab + b * IMG_W;
            #pragma unroll
            for (int j = 0; j < 4; ++j) {
                const int x = xq * 4 + j;
                const int4 cc = ctb[x];
                const int c0 = cc.x;
                const int c1 = cc.y;
                const float wc = __int_as_float(cc.z);
                const float omwc = 1.0f - wc;
                const float v00 = p[r0 * IMG_W + c0];
                const float v10 = p[r1 * IMG_W + c0];
                const float v01 = p[r0 * IMG_W + c1];
                const float v11 = p[r1 * IMG_W + c1];
                const float rb0 = v00 * omwr + v10 * wr;
                const float rb1 = v01 * omwr + v11 * wr;
                const float patch = rb0 * omwc + rb1 * wc;
                (&res.x)[j] = (&base.x)[j] * 0.6f + patch * 0.4f;
            }
        }
        ((float4*)out)[chunk] = res;
    }
}

extern "C" void kernel_launch(void* const* d_in, const int* in_sizes, int n_in,
                              void* d_out, int out_size, void* d_ws, size_t ws_size,
                              hipStream_t stream) {
    const float* images = (const float*)d_in[0];
    const float* atten  = (const float*)d_in[1];
    float* out = (float*)d_out;
    // workspace layout:
    //   [0, 16384)            strip_box: 32 * 32 * 4 ints
    //   [16384, 262144)       rowtab: 32 * 480 int4 (w = full-crop flag)
    //   [262144, 507904)      coltab: 32 * 480 int4
    int* strip_box = (int*)d_ws;
    int4* rowtab = (int4*)((char*)d_ws + 16384);
    int4* coltab = (int4*)((char*)d_ws + 16384 + 32 * IMG_H * (int)sizeof(int4));

    dim3 mgrid(STRIPS, NB);
    mask_kernel<<<mgrid, 256, 0, stream>>>(atten, strip_box);

    prep_kernel<<<dim3(NB), 512, 0, stream>>>(strip_box, rowtab, coltab);

    blend_kernel<<<dim3(2048), 256, 0, stream>>>(images, rowtab, coltab, out);
}